// Round 10
// baseline (6859.393 us; speedup 1.0000x reference)
//
#include <hip/hip_runtime.h>
#include <hip/hip_bf16.h>

typedef __bf16 bf16x8 __attribute__((ext_vector_type(8)));
typedef float f32x4 __attribute__((ext_vector_type(4)));
typedef float f32x4v __attribute__((ext_vector_type(4)));
typedef int   i32x4 __attribute__((ext_vector_type(4)));

#define M_DIM 8192
#define K_DIM 4096
#define N_DIM 11008
#define KW 512
#define NG 32
#define NTI 32           // K-tiles of 128 (one quant group each)

#define GLOAD_LDS16(g, l) \
  __builtin_amdgcn_global_load_lds((const __attribute__((address_space(1))) void*)(g), \
                                   (__attribute__((address_space(3))) void*)(l), 16, 0, 0)

// ---------------- prepass 1: x fp32 -> i8 with per-row scale ----------------
__global__ __launch_bounds__(256) void quant_x_i8(
    const float* __restrict__ x, signed char* __restrict__ xq,
    float* __restrict__ sxs)
{
    const int row = blockIdx.x;
    const int t   = threadIdx.x;
    const f32x4v* xr = reinterpret_cast<const f32x4v*>(x + (size_t)row * K_DIM);

    f32x4v v[4];
    float am = 0.f;
    #pragma unroll
    for (int i = 0; i < 4; ++i) {
        v[i] = __builtin_nontemporal_load(xr + t * 4 + i);
        #pragma unroll
        for (int j = 0; j < 4; ++j) am = fmaxf(am, fabsf(v[i][j]));
    }
    #pragma unroll
    for (int off = 32; off; off >>= 1) am = fmaxf(am, __shfl_xor(am, off));
    __shared__ float red[4];
    const int lane = t & 63, w = t >> 6;
    if (lane == 0) red[w] = am;
    __syncthreads();
    am = fmaxf(fmaxf(red[0], red[1]), fmaxf(red[2], red[3]));
    const float inv = am > 1e-30f ? 127.f / am : 0.f;
    if (t == 0) sxs[row] = am > 1e-30f ? am / 127.f : 0.f;

    i32x4 o;
    #pragma unroll
    for (int i = 0; i < 4; ++i) {
        int p = 0;
        #pragma unroll
        for (int j = 0; j < 4; ++j)
            p |= (((int)__builtin_rintf(v[i][j] * inv)) & 255) << (8 * j);
        o[i] = p;
    }
    reinterpret_cast<i32x4*>(xq + (size_t)row * K_DIM)[t] = o;
}

// ---------------- prepass 2: qweight int4 -> i8 (nib - z), exact ----------------
__global__ __launch_bounds__(256) void dequant_w_i8(
    const unsigned int* __restrict__ qw, const int* __restrict__ qz,
    signed char* __restrict__ wq)
{
    size_t idx = (size_t)blockIdx.x * 256 + threadIdx.x;   // one u32 -> 8 i8
    unsigned int q = __builtin_nontemporal_load(qw + idx);
    int row = (int)(idx >> 9);
    int g   = ((int)idx & 511) >> 4;
    int z   = qz[row * NG + g];
    int lo = 0, hi = 0;
    #pragma unroll
    for (int j = 0; j < 4; ++j)
        lo |= ((((int)((q >> (4 * j)) & 15u)) - z) & 255) << (8 * j);
    #pragma unroll
    for (int j = 0; j < 4; ++j)
        hi |= ((((int)((q >> (16 + 4 * j)) & 15u)) - z) & 255) << (8 * j);
    reinterpret_cast<int2*>(wq)[idx] = make_int2(lo, hi);
}

// ---------------- main: 256x128 4-phase i8 GEMM, BK=128 (= one group) ----------------
// sA[buf][ks][256][64 i8] = 64 KiB, sB[buf][ks][128][64] = 32 KiB.
// 16B-slot swizzle within 64B row: phys = logical ^ ((row>>1)&3).
// 8 waves = 4M x 2N, wave tile 64x64.
// acci is PHASE-LOCAL (r9 lesson): each phase's 16 MFMAs start from zero and are
// converted into accf immediately (both ks-halves share the tile's group scale).
// Only accf (64 f32) + scg (8) survive a barrier -> no cross-phase register blowup.
//   P1: compute b0.ks0 conv(g0), stage b1.ks1(t1) | P2: b0.ks1 conv(g0), stage b0.ks0(t2)
//   P3: compute b1.ks0 conv(g1), stage b0.ks1(t2) | P4: b1.ks1 conv(g1), stage b1.ks0(t3)
// vmcnt(6) at EVERY phase end: each staged sub-tile has exactly 6 younger
// stage-loads at its covering gate.

#define STAGE_A(SBUF, SKS, STILE)                                                 \
  do {                                                                            \
    _Pragma("unroll")                                                             \
    for (int j_ = 0; j_ < 2; ++j_) {                                              \
      int srow_ = j_ * 128 + w * 16 + (lane >> 2);                                \
      GLOAD_LDS16(Aq + (size_t)(m0 + srow_) * K_DIM + (STILE) * 128 + (SKS) * 64 + sslotg * 16, \
                  &sA[SBUF][SKS][j_ * 128 + w * 16][0]);                          \
    }                                                                             \
  } while (0)

#define STAGE_B(SBUF, SKS, STILE)                                                 \
  do {                                                                            \
    int srow_ = w * 16 + (lane >> 2);                                             \
    GLOAD_LDS16(Bq + (size_t)(n0 + srow_) * K_DIM + (STILE) * 128 + (SKS) * 64 + sslotg * 16, \
                &sB[SBUF][SKS][w * 16][0]);                                       \
  } while (0)

#define PHASE(BUF, KS, SBUF, SKS, STILE, SCG)                                     \
  do {                                                                            \
    i32x4 af_[4];                                                                 \
    i32x4 bcur_[4];                                                               \
    _Pragma("unroll")                                                             \
    for (int m_ = 0; m_ < 4; ++m_) {                                              \
      int row_ = wm * 64 + m_ * 16 + lane16;                                      \
      af_[m_] = *reinterpret_cast<const i32x4*>(&sA[BUF][KS][row_][colByte]);     \
    }                                                                             \
    _Pragma("unroll")                                                             \
    for (int n_ = 0; n_ < 4; ++n_) {                                              \
      int row_ = wn * 64 + n_ * 16 + lane16;                                      \
      bcur_[n_] = *reinterpret_cast<const i32x4*>(&sB[BUF][KS][row_][colByte]);   \
    }                                                                             \
    STAGE_A(SBUF, SKS, STILE);                                                    \
    STAGE_B(SBUF, SKS, STILE);                                                    \
    __builtin_amdgcn_s_barrier();                                                 \
    i32x4 acci_[4][4];                                                            \
    __builtin_amdgcn_s_setprio(1);                                                \
    _Pragma("unroll")                                                             \
    for (int m_ = 0; m_ < 4; ++m_)                                                \
      _Pragma("unroll")                                                           \
      for (int n_ = 0; n_ < 4; ++n_)                                              \
        acci_[m_][n_] = __builtin_amdgcn_mfma_i32_16x16x64_i8(                    \
            af_[m_], bcur_[n_], (i32x4){0, 0, 0, 0}, 0, 0, 0);                    \
    __builtin_amdgcn_s_setprio(0);                                                \
    _Pragma("unroll")                                                             \
    for (int m_ = 0; m_ < 4; ++m_)                                                \
      _Pragma("unroll")                                                           \
      for (int n_ = 0; n_ < 4; ++n_) {                                            \
        float s_ = SCG[n_];                                                       \
        _Pragma("unroll")                                                         \
        for (int r_ = 0; r_ < 4; ++r_)                                            \
          accf[m_][n_][r_] += (float)acci_[m_][n_][r_] * s_;                      \
      }                                                                           \
    asm volatile("s_waitcnt vmcnt(6)" ::: "memory");                              \
    __builtin_amdgcn_s_barrier();                                                 \
  } while (0)

__global__ __launch_bounds__(512, 1) void gemm_i8_4phase(
    const signed char* __restrict__ Aq, const signed char* __restrict__ Bq,
    const float* __restrict__ scales, const float* __restrict__ sxs,
    float* __restrict__ out)
{
    __shared__ __attribute__((aligned(16))) signed char sA[2][2][256][64];  // 64 KiB
    __shared__ __attribute__((aligned(16))) signed char sB[2][2][128][64];  // 32 KiB

    const int t      = threadIdx.x;
    const int lane   = t & 63;
    const int w      = t >> 6;        // wave 0..7
    const int wm     = w >> 1;        // 0..3 -> 64-row M band
    const int wn     = w & 1;         // 0..1 -> 64-col N band
    const int lane16 = lane & 15;
    const int psl    = (lane >> 4) ^ ((lane16 >> 1) & 3);   // read physical 16B slot
    const int colByte = psl * 16;
    const int sslotg = (lane & 3) ^ ((lane >> 3) & 3);      // stage source slot
    const int cl     = lane & 15;

    // XCD swizzle: 2752 = 8 x 344
    int bid = blockIdx.x;
    int wg  = (bid & 7) * 344 + (bid >> 3);
    int bm  = wg / 86;
    int bn  = wg - bm * 86;
    const int m0 = bm * 256;
    const int n0 = bn * 128;

    f32x4 accf[4][4] = {};
    float scg0[4], scg1[4];

    // prologue: buf0 <- tile0 (ks0, ks1); buf1 <- tile1 ks0
    STAGE_A(0, 0, 0); STAGE_B(0, 0, 0);
    STAGE_A(0, 1, 0); STAGE_B(0, 1, 0);
    STAGE_A(1, 0, 1); STAGE_B(1, 0, 1);
    asm volatile("s_waitcnt vmcnt(6)" ::: "memory");
    __builtin_amdgcn_s_barrier();

    for (int it = 0; it < NTI / 2; ++it) {
        const int g0 = it * 2;             // group of buf0's tile
        const int t1 = it * 2 + 1;
        const int t2 = (it * 2 + 2) & (NTI - 1);
        const int t3 = (it * 2 + 3) & (NTI - 1);

        // group scales (g0, g0+1) as float2 per n-frag
        #pragma unroll
        for (int n_ = 0; n_ < 4; ++n_) {
            int coln = n0 + wn * 64 + n_ * 16 + cl;
            float2 sv = *reinterpret_cast<const float2*>(&scales[(size_t)coln * NG + g0]);
            scg0[n_] = sv.x;
            scg1[n_] = sv.y;
        }

        //    compute      | stage          | scale
        PHASE(0, 0,          1, 1, t1,        scg0);   // P1
        PHASE(0, 1,          0, 0, t2,        scg0);   // P2
        PHASE(1, 0,          0, 1, t2,        scg1);   // P3
        PHASE(1, 1,          1, 0, t3,        scg1);   // P4
    }

    asm volatile("s_waitcnt vmcnt(0)" ::: "memory");   // drain tail stages

    // epilogue: C/D col=lane&15, row=(lane>>4)*4+r; fold per-row x-scale
    const int rq = lane >> 4;
    #pragma unroll
    for (int m = 0; m < 4; ++m) {
        #pragma unroll
        for (int n = 0; n < 4; ++n) {
            int col = n0 + wn * 64 + n * 16 + cl;
            #pragma unroll
            for (int r = 0; r < 4; ++r) {
                int row = m0 + wm * 64 + m * 16 + rq * 4 + r;
                out[(size_t)row * N_DIM + col] = accf[m][n][r] * sxs[row];
            }
        }
    }
}

// ---------------- fallback: round-1 fused bf16 kernel (128^2) ----------------
#define BM 128
#define BN 128
#define BK 64
#define KSTEPS (K_DIM / BK)

__global__ __launch_bounds__(256) void TurboQuantLinear_gemm_dq(
    const float* __restrict__ x,
    const unsigned int* __restrict__ qw,
    const float* __restrict__ scales,
    const int* __restrict__ qzeros,
    float* __restrict__ out)
{
    __shared__ __bf16 As[BM * BK];
    __shared__ __bf16 Bs[BN * BK];

    const int t    = threadIdx.x;
    const int lane = t & 63;
    const int wave = t >> 6;
    const int wr   = wave >> 1;
    const int wc   = wave & 1;
    const int m0 = blockIdx.x * BM;
    const int n0 = blockIdx.y * BN;

    f32x4 acc[4][4] = {};

    for (int kt = 0; kt < KSTEPS; ++kt) {
        const int k0 = kt * BK;
        const int g  = k0 >> 7;

        #pragma unroll
        for (int i = 0; i < 4; ++i) {
            int o  = t + i * 256;
            int r  = o >> 3;
            int c8 = o & 7;
            const float4* src = reinterpret_cast<const float4*>(
                &x[(size_t)(m0 + r) * K_DIM + k0 + c8 * 8]);
            float4 f0 = src[0];
            float4 f1 = src[1];
            bf16x8 v;
            v[0] = (__bf16)f0.x; v[1] = (__bf16)f0.y; v[2] = (__bf16)f0.z; v[3] = (__bf16)f0.w;
            v[4] = (__bf16)f1.x; v[5] = (__bf16)f1.y; v[6] = (__bf16)f1.z; v[7] = (__bf16)f1.w;
            int slot = c8 ^ (r & 7);
            *reinterpret_cast<bf16x8*>(&As[r * BK + slot * 8]) = v;
        }

        const int kw0 = kt * 8;
        #pragma unroll
        for (int i = 0; i < 4; ++i) {
            int idx = t + i * 256;
            int r   = idx >> 3;
            int wq2 = idx & 7;
            unsigned int q = qw[(size_t)(n0 + r) * KW + kw0 + wq2];
            float s  = scales[(n0 + r) * NG + g];
            float z  = (float)qzeros[(n0 + r) * NG + g];
            float zs = z * s;
            bf16x8 v;
            #pragma unroll
            for (int j = 0; j < 8; ++j) {
                float val = (float)((q >> (4 * j)) & 15u) * s - zs;
                v[j] = (__bf16)val;
            }
            int slot = wq2 ^ (r & 7);
            *reinterpret_cast<bf16x8*>(&Bs[r * BK + slot * 8]) = v;
        }

        __syncthreads();

        const int row_in_l = lane & 15;
        #pragma unroll
        for (int kk = 0; kk < 2; ++kk) {
            const int kslot = kk * 4 + (lane >> 4);
            bf16x8 af[4], bfr[4];
            #pragma unroll
            for (int m = 0; m < 4; ++m) {
                int row = wr * 64 + m * 16 + row_in_l;
                af[m] = *reinterpret_cast<const bf16x8*>(
                    &As[row * BK + ((kslot ^ (row & 7)) * 8)]);
            }
            #pragma unroll
            for (int n = 0; n < 4; ++n) {
                int row = wc * 64 + n * 16 + row_in_l;
                bfr[n] = *reinterpret_cast<const bf16x8*>(
                    &Bs[row * BK + ((kslot ^ (row & 7)) * 8)]);
            }
            #pragma unroll
            for (int m = 0; m < 4; ++m)
                #pragma unroll
                for (int n = 0; n < 4; ++n)
                    acc[m][n] = __builtin_amdgcn_mfma_f32_16x16x32_bf16(
                        af[m], bfr[n], acc[m][n], 0, 0, 0);
        }

        __syncthreads();
    }

    const int cl2 = lane & 15;
    const int rq = lane >> 4;
    #pragma unroll
    for (int m = 0; m < 4; ++m) {
        #pragma unroll
        for (int n = 0; n < 4; ++n) {
            int col = n0 + wc * 64 + n * 16 + cl2;
            #pragma unroll
            for (int r = 0; r < 4; ++r) {
                int row = m0 + wr * 64 + m * 16 + rq * 4 + r;
                out[(size_t)row * N_DIM + col] = acc[m][n][r];
            }
        }
    }
}

extern "C" void kernel_launch(void* const* d_in, const int* in_sizes, int n_in,
                              void* d_out, int out_size, void* d_ws, size_t ws_size,
                              hipStream_t stream) {
    const float*        x      = (const float*)d_in[0];
    const unsigned int* qw     = (const unsigned int*)d_in[1];
    const float*        scales = (const float*)d_in[2];
    const int*          qzeros = (const int*)d_in[3];
    float* out = (float*)d_out;

    const size_t xq_bytes  = (size_t)M_DIM * K_DIM;          // 32 MiB
    const size_t wq_bytes  = (size_t)N_DIM * K_DIM;          // 43 MiB
    const size_t sxs_bytes = (size_t)M_DIM * sizeof(float);  // 32 KiB

    if (ws_size >= xq_bytes + wq_bytes + sxs_bytes) {
        signed char* xq  = (signed char*)d_ws;
        signed char* wqb = (signed char*)d_ws + xq_bytes;
        float*       sxs = (float*)((char*)d_ws + xq_bytes + wq_bytes);

        quant_x_i8<<<dim3(M_DIM), dim3(256), 0, stream>>>(x, xq, sxs);
        dequant_w_i8<<<dim3((N_DIM * KW) / 256), dim3(256), 0, stream>>>(qw, qzeros, wqb);

        // 32 x 86 = 2752 workgroups, XCD-swizzled inside the kernel (2752 = 8*344)
        gemm_i8_4phase<<<dim3(2752), dim3(512), 0, stream>>>(xq, wqb, scales, sxs, out);
    } else {
        dim3 grid(M_DIM / BM, N_DIM / BN);
        TurboQuantLinear_gemm_dq<<<grid, dim3(256), 0, stream>>>(x, qw, scales, qzeros, out);
    }
}

// Round 11
// 817.890 us; speedup vs baseline: 8.3867x; 8.3867x over previous
//
#include <hip/hip_runtime.h>
#include <hip/hip_bf16.h>

typedef __bf16 bf16x8 __attribute__((ext_vector_type(8)));
typedef float f32x4 __attribute__((ext_vector_type(4)));
typedef float f32x4v __attribute__((ext_vector_type(4)));
typedef int   i32x4 __attribute__((ext_vector_type(4)));

#define M_DIM 8192
#define K_DIM 4096
#define N_DIM 11008
#define KW 512
#define NG 32
#define NTI 32           // K-tiles of 128 (one quant group each)

#define GLOAD_LDS16(g, l) \
  __builtin_amdgcn_global_load_lds((const __attribute__((address_space(1))) void*)(g), \
                                   (__attribute__((address_space(3))) void*)(l), 16, 0, 0)

// ---------------- prepass 1: x fp32 -> i8 with per-row scale ----------------
__global__ __launch_bounds__(256) void quant_x_i8(
    const float* __restrict__ x, signed char* __restrict__ xq,
    float* __restrict__ sxs)
{
    const int row = blockIdx.x;
    const int t   = threadIdx.x;
    const f32x4v* xr = reinterpret_cast<const f32x4v*>(x + (size_t)row * K_DIM);

    f32x4v v[4];
    float am = 0.f;
    #pragma unroll
    for (int i = 0; i < 4; ++i) {
        v[i] = __builtin_nontemporal_load(xr + t * 4 + i);
        #pragma unroll
        for (int j = 0; j < 4; ++j) am = fmaxf(am, fabsf(v[i][j]));
    }
    #pragma unroll
    for (int off = 32; off; off >>= 1) am = fmaxf(am, __shfl_xor(am, off));
    __shared__ float red[4];
    const int lane = t & 63, w = t >> 6;
    if (lane == 0) red[w] = am;
    __syncthreads();
    am = fmaxf(fmaxf(red[0], red[1]), fmaxf(red[2], red[3]));
    const float inv = am > 1e-30f ? 127.f / am : 0.f;
    if (t == 0) sxs[row] = am > 1e-30f ? am / 127.f : 0.f;

    i32x4 o;
    #pragma unroll
    for (int i = 0; i < 4; ++i) {
        int p = 0;
        #pragma unroll
        for (int j = 0; j < 4; ++j)
            p |= (((int)__builtin_rintf(v[i][j] * inv)) & 255) << (8 * j);
        o[i] = p;
    }
    reinterpret_cast<i32x4*>(xq + (size_t)row * K_DIM)[t] = o;
}

// ---------------- prepass 2: qweight int4 -> i8 (nib - z), exact ----------------
__global__ __launch_bounds__(256) void dequant_w_i8(
    const unsigned int* __restrict__ qw, const int* __restrict__ qz,
    signed char* __restrict__ wq)
{
    size_t idx = (size_t)blockIdx.x * 256 + threadIdx.x;   // one u32 -> 8 i8
    unsigned int q = __builtin_nontemporal_load(qw + idx);
    int row = (int)(idx >> 9);
    int g   = ((int)idx & 511) >> 4;
    int z   = qz[row * NG + g];
    int lo = 0, hi = 0;
    #pragma unroll
    for (int j = 0; j < 4; ++j)
        lo |= ((((int)((q >> (4 * j)) & 15u)) - z) & 255) << (8 * j);
    #pragma unroll
    for (int j = 0; j < 4; ++j)
        hi |= ((((int)((q >> (16 + 4 * j)) & 15u)) - z) & 255) << (8 * j);
    reinterpret_cast<int2*>(wq)[idx] = make_int2(lo, hi);
}

// ---------------- main: 128x128 4-phase i8 GEMM, BK=128 (= one group) ----------------
// sA[buf][ks][128][64 i8] = 32 KiB, sB same = 32 KiB; 64 KiB total.
// 16B-slot swizzle within 64B row: phys = logical ^ ((row>>1)&3).
// 8 waves = 2M x 4N, wave tile 64x32 -> accf[4][2] (32 f32) + acci[4][2] (32 i32,
// MFMA-chained across the ks pair, converted once per K-tile). Arch-side live
// ~112 regs < the measured 128 cap (r7-r10: VGPR_Count pinned at 128; any design
// over that spills GBs of scratch).
//   P1: compute b0.ks0 (zero-init acci), stage b1.ks1(t1)
//   P2: compute b0.ks1 (chain), conv scg0,  stage b0.ks0(t2)
//   P3: compute b1.ks0 (zero-init),         stage b0.ks1(t2)
//   P4: compute b1.ks1 (chain), conv scg1,  stage b1.ks0(t3)
// 2 gloads/phase; vmcnt(4) at every phase end (each staged sub-tile has exactly
// 4 younger stage-loads at its covering gate; scg loads only tighten).

#define STAGE_A(SBUF, SKS, STILE)                                                 \
  do {                                                                            \
    int srow_ = w * 16 + (lane >> 2);                                             \
    GLOAD_LDS16(Aq + (size_t)(m0 + srow_) * K_DIM + (STILE) * 128 + (SKS) * 64 + sslotg * 16, \
                &sA[SBUF][SKS][w * 16][0]);                                       \
  } while (0)

#define STAGE_B(SBUF, SKS, STILE)                                                 \
  do {                                                                            \
    int srow_ = w * 16 + (lane >> 2);                                             \
    GLOAD_LDS16(Bq + (size_t)(n0 + srow_) * K_DIM + (STILE) * 128 + (SKS) * 64 + sslotg * 16, \
                &sB[SBUF][SKS][w * 16][0]);                                       \
  } while (0)

#define PHASE(BUF, KS, SBUF, SKS, STILE, DO_CONV, SCG)                            \
  do {                                                                            \
    i32x4 af_[4];                                                                 \
    i32x4 bcur_[2];                                                               \
    _Pragma("unroll")                                                             \
    for (int m_ = 0; m_ < 4; ++m_) {                                              \
      int row_ = wm * 64 + m_ * 16 + lane16;                                      \
      af_[m_] = *reinterpret_cast<const i32x4*>(&sA[BUF][KS][row_][colByte]);     \
    }                                                                             \
    _Pragma("unroll")                                                             \
    for (int n_ = 0; n_ < 2; ++n_) {                                              \
      int row_ = wn * 32 + n_ * 16 + lane16;                                      \
      bcur_[n_] = *reinterpret_cast<const i32x4*>(&sB[BUF][KS][row_][colByte]);   \
    }                                                                             \
    STAGE_A(SBUF, SKS, STILE);                                                    \
    STAGE_B(SBUF, SKS, STILE);                                                    \
    __builtin_amdgcn_s_barrier();                                                 \
    __builtin_amdgcn_s_setprio(1);                                                \
    _Pragma("unroll")                                                             \
    for (int m_ = 0; m_ < 4; ++m_)                                                \
      _Pragma("unroll")                                                           \
      for (int n_ = 0; n_ < 2; ++n_) {                                            \
        if ((KS) == 0)                                                            \
          acci[m_][n_] = __builtin_amdgcn_mfma_i32_16x16x64_i8(                   \
              af_[m_], bcur_[n_], (i32x4){0, 0, 0, 0}, 0, 0, 0);                  \
        else                                                                      \
          acci[m_][n_] = __builtin_amdgcn_mfma_i32_16x16x64_i8(                   \
              af_[m_], bcur_[n_], acci[m_][n_], 0, 0, 0);                         \
      }                                                                           \
    __builtin_amdgcn_s_setprio(0);                                                \
    if (DO_CONV) {                                                                \
      _Pragma("unroll")                                                           \
      for (int m_ = 0; m_ < 4; ++m_)                                              \
        _Pragma("unroll")                                                         \
        for (int n_ = 0; n_ < 2; ++n_) {                                          \
          float s_ = SCG[n_];                                                     \
          _Pragma("unroll")                                                       \
          for (int r_ = 0; r_ < 4; ++r_)                                          \
            accf[m_][n_][r_] += (float)acci[m_][n_][r_] * s_;                     \
        }                                                                         \
    }                                                                             \
    asm volatile("s_waitcnt vmcnt(4)" ::: "memory");                              \
    __builtin_amdgcn_s_barrier();                                                 \
  } while (0)

__global__ __launch_bounds__(512, 1) void gemm_i8_128(
    const signed char* __restrict__ Aq, const signed char* __restrict__ Bq,
    const float* __restrict__ scales, const float* __restrict__ sxs,
    float* __restrict__ out)
{
    __shared__ __attribute__((aligned(16))) signed char sA[2][2][128][64];  // 32 KiB
    __shared__ __attribute__((aligned(16))) signed char sB[2][2][128][64];  // 32 KiB

    const int t      = threadIdx.x;
    const int lane   = t & 63;
    const int w      = t >> 6;        // wave 0..7
    const int wm     = w >> 2;        // 0..1 -> 64-row M band
    const int wn     = w & 3;         // 0..3 -> 32-col N band
    const int lane16 = lane & 15;
    const int psl    = (lane >> 4) ^ ((lane16 >> 1) & 3);   // read physical 16B slot
    const int colByte = psl * 16;
    const int sslotg = (lane & 3) ^ ((lane >> 3) & 3);      // stage source slot
    const int cl     = lane & 15;

    // XCD swizzle: 5504 = 8 x 688
    int bid = blockIdx.x;
    int wg  = (bid & 7) * 688 + (bid >> 3);
    int bm  = wg / 86;
    int bn  = wg - bm * 86;
    const int m0 = bm * 128;
    const int n0 = bn * 128;

    f32x4 accf[4][2] = {};
    i32x4 acci[4][2];
    float scg0[2], scg1[2];

    // prologue: buf0 <- tile0 (ks0, ks1); buf1 <- tile1 ks0  (6 loads)
    STAGE_A(0, 0, 0); STAGE_B(0, 0, 0);
    STAGE_A(0, 1, 0); STAGE_B(0, 1, 0);
    STAGE_A(1, 0, 1); STAGE_B(1, 0, 1);
    asm volatile("s_waitcnt vmcnt(4)" ::: "memory");
    __builtin_amdgcn_s_barrier();

    for (int it = 0; it < NTI / 2; ++it) {
        const int g0 = it * 2;             // group of buf0's tile
        const int t1 = it * 2 + 1;
        const int t2 = (it * 2 + 2) & (NTI - 1);
        const int t3 = (it * 2 + 3) & (NTI - 1);

        // group scales (g0, g0+1) as float2 per n-frag
        #pragma unroll
        for (int n_ = 0; n_ < 2; ++n_) {
            int coln = n0 + wn * 32 + n_ * 16 + cl;
            float2 sv = *reinterpret_cast<const float2*>(&scales[(size_t)coln * NG + g0]);
            scg0[n_] = sv.x;
            scg1[n_] = sv.y;
        }

        //    compute      | stage          | conv scale
        PHASE(0, 0,          1, 1, t1,        0, scg0);   // P1
        PHASE(0, 1,          0, 0, t2,        1, scg0);   // P2: conv g0
        PHASE(1, 0,          0, 1, t2,        0, scg1);   // P3
        PHASE(1, 1,          1, 0, t3,        1, scg1);   // P4: conv g1
    }

    asm volatile("s_waitcnt vmcnt(0)" ::: "memory");   // drain tail stages

    // epilogue: C/D col=lane&15, row=(lane>>4)*4+r; fold per-row x-scale
    const int rq = lane >> 4;
    #pragma unroll
    for (int m = 0; m < 4; ++m) {
        #pragma unroll
        for (int n = 0; n < 2; ++n) {
            int col = n0 + wn * 32 + n * 16 + cl;
            #pragma unroll
            for (int r = 0; r < 4; ++r) {
                int row = m0 + wm * 64 + m * 16 + rq * 4 + r;
                out[(size_t)row * N_DIM + col] = accf[m][n][r] * sxs[row];
            }
        }
    }
}

// ---------------- fallback: round-1 fused bf16 kernel (128^2) ----------------
#define BM 128
#define BN 128
#define BK 64
#define KSTEPS (K_DIM / BK)

__global__ __launch_bounds__(256) void TurboQuantLinear_gemm_dq(
    const float* __restrict__ x,
    const unsigned int* __restrict__ qw,
    const float* __restrict__ scales,
    const int* __restrict__ qzeros,
    float* __restrict__ out)
{
    __shared__ __bf16 As[BM * BK];
    __shared__ __bf16 Bs[BN * BK];

    const int t    = threadIdx.x;
    const int lane = t & 63;
    const int wave = t >> 6;
    const int wr   = wave >> 1;
    const int wc   = wave & 1;
    const int m0 = blockIdx.x * BM;
    const int n0 = blockIdx.y * BN;

    f32x4 acc[4][4] = {};

    for (int kt = 0; kt < KSTEPS; ++kt) {
        const int k0 = kt * BK;
        const int g  = k0 >> 7;

        #pragma unroll
        for (int i = 0; i < 4; ++i) {
            int o  = t + i * 256;
            int r  = o >> 3;
            int c8 = o & 7;
            const float4* src = reinterpret_cast<const float4*>(
                &x[(size_t)(m0 + r) * K_DIM + k0 + c8 * 8]);
            float4 f0 = src[0];
            float4 f1 = src[1];
            bf16x8 v;
            v[0] = (__bf16)f0.x; v[1] = (__bf16)f0.y; v[2] = (__bf16)f0.z; v[3] = (__bf16)f0.w;
            v[4] = (__bf16)f1.x; v[5] = (__bf16)f1.y; v[6] = (__bf16)f1.z; v[7] = (__bf16)f1.w;
            int slot = c8 ^ (r & 7);
            *reinterpret_cast<bf16x8*>(&As[r * BK + slot * 8]) = v;
        }

        const int kw0 = kt * 8;
        #pragma unroll
        for (int i = 0; i < 4; ++i) {
            int idx = t + i * 256;
            int r   = idx >> 3;
            int wq2 = idx & 7;
            unsigned int q = qw[(size_t)(n0 + r) * KW + kw0 + wq2];
            float s  = scales[(n0 + r) * NG + g];
            float z  = (float)qzeros[(n0 + r) * NG + g];
            float zs = z * s;
            bf16x8 v;
            #pragma unroll
            for (int j = 0; j < 8; ++j) {
                float val = (float)((q >> (4 * j)) & 15u) * s - zs;
                v[j] = (__bf16)val;
            }
            int slot = wq2 ^ (r & 7);
            *reinterpret_cast<bf16x8*>(&Bs[r * BK + slot * 8]) = v;
        }

        __syncthreads();

        const int row_in_l = lane & 15;
        #pragma unroll
        for (int kk = 0; kk < 2; ++kk) {
            const int kslot = kk * 4 + (lane >> 4);
            bf16x8 af[4], bfr[4];
            #pragma unroll
            for (int m = 0; m < 4; ++m) {
                int row = wr * 64 + m * 16 + row_in_l;
                af[m] = *reinterpret_cast<const bf16x8*>(
                    &As[row * BK + ((kslot ^ (row & 7)) * 8)]);
            }
            #pragma unroll
            for (int n = 0; n < 4; ++n) {
                int row = wc * 64 + n * 16 + row_in_l;
                bfr[n] = *reinterpret_cast<const bf16x8*>(
                    &Bs[row * BK + ((kslot ^ (row & 7)) * 8)]);
            }
            #pragma unroll
            for (int m = 0; m < 4; ++m)
                #pragma unroll
                for (int n = 0; n < 4; ++n)
                    acc[m][n] = __builtin_amdgcn_mfma_f32_16x16x32_bf16(
                        af[m], bfr[n], acc[m][n], 0, 0, 0);
        }

        __syncthreads();
    }

    const int cl2 = lane & 15;
    const int rq = lane >> 4;
    #pragma unroll
    for (int m = 0; m < 4; ++m) {
        #pragma unroll
        for (int n = 0; n < 4; ++n) {
            int col = n0 + wc * 64 + n * 16 + cl2;
            #pragma unroll
            for (int r = 0; r < 4; ++r) {
                int row = m0 + wr * 64 + m * 16 + rq * 4 + r;
                out[(size_t)row * N_DIM + col] = acc[m][n][r];
            }
        }
    }
}

extern "C" void kernel_launch(void* const* d_in, const int* in_sizes, int n_in,
                              void* d_out, int out_size, void* d_ws, size_t ws_size,
                              hipStream_t stream) {
    const float*        x      = (const float*)d_in[0];
    const unsigned int* qw     = (const unsigned int*)d_in[1];
    const float*        scales = (const float*)d_in[2];
    const int*          qzeros = (const int*)d_in[3];
    float* out = (float*)d_out;

    const size_t xq_bytes  = (size_t)M_DIM * K_DIM;          // 32 MiB
    const size_t wq_bytes  = (size_t)N_DIM * K_DIM;          // 43 MiB
    const size_t sxs_bytes = (size_t)M_DIM * sizeof(float);  // 32 KiB

    if (ws_size >= xq_bytes + wq_bytes + sxs_bytes) {
        signed char* xq  = (signed char*)d_ws;
        signed char* wqb = (signed char*)d_ws + xq_bytes;
        float*       sxs = (float*)((char*)d_ws + xq_bytes + wq_bytes);

        quant_x_i8<<<dim3(M_DIM), dim3(256), 0, stream>>>(x, xq, sxs);
        dequant_w_i8<<<dim3((N_DIM * KW) / 256), dim3(256), 0, stream>>>(qw, qzeros, wqb);

        // 64 x 86 = 5504 workgroups, XCD-swizzled inside the kernel (5504 = 8*688)
        gemm_i8_128<<<dim3(5504), dim3(512), 0, stream>>>(xq, wqb, scales, sxs, out);
    } else {
        dim3 grid(M_DIM / BM, N_DIM / BN);
        TurboQuantLinear_gemm_dq<<<grid, dim3(256), 0, stream>>>(x, qw, scales, qzeros, out);
    }
}